// Round 18
// baseline (128.581 us; speedup 1.0000x reference)
//
#include <hip/hip_runtime.h>

#define KDIM 128
#define NTOT (KDIM * KDIM * KDIM)
#define BPD 16          // bins per dim
#define NBINS (BPD * BPD * BPD)
#define TILE_D 11       // 8 + 3 halo
#define T2 (TILE_D * TILE_D)
#define TILE_N (TILE_D * TILE_D * TILE_D)
#define TPAD 1332       // per-wave LDS tile stride (floats)
#define TSTRIDE 1344    // padded global tile stride (floats)
#define CHUNK 256
#define NZKEEP 65       // Hermitian: keep z-planes 0..64
#define NSCALE_BLK (NZKEEP * 8)
#define ST 17           // LDS row stride (float2) for x transpose stage
#define ZST 17          // z-phi LDS row stride (floats)

static constexpr float PI_F = 3.14159265358979323846f;
static constexpr float TWO_PI_F = 6.28318530717958647692f;
static constexpr float KE_F = 14.3996f;
static constexpr float ALPHA_F = 0.35f;

__device__ __forceinline__ int brev7(int i) { return (int)(__brev((unsigned)i) >> 25); }

struct pf4 { float a, b, c, d; };
__device__ __forceinline__ pf4 ld4u(const float* p) {
    pf4 v;
    __builtin_memcpy(&v, p, 16);
    return v;
}

__device__ __forceinline__ void inv3x3(const float* c, float* inv, float* adet) {
    float a00 = c[0], a01 = c[1], a02 = c[2];
    float a10 = c[3], a11 = c[4], a12 = c[5];
    float a20 = c[6], a21 = c[7], a22 = c[8];
    float det = a00 * (a11 * a22 - a12 * a21) - a01 * (a10 * a22 - a12 * a20) +
                a02 * (a10 * a21 - a11 * a20);
    float id = 1.0f / det;
    inv[0] = (a11 * a22 - a12 * a21) * id;
    inv[1] = (a02 * a21 - a01 * a22) * id;
    inv[2] = (a01 * a12 - a02 * a11) * id;
    inv[3] = (a12 * a20 - a10 * a22) * id;
    inv[4] = (a00 * a22 - a02 * a20) * id;
    inv[5] = (a02 * a10 - a00 * a12) * id;
    inv[6] = (a10 * a21 - a11 * a20) * id;
    inv[7] = (a01 * a20 - a00 * a21) * id;
    inv[8] = (a00 * a11 - a01 * a10) * id;
    *adet = fabsf(det);
}

__device__ __forceinline__ void bspline4(float f, float* w, float* dw) {
    float f2 = f * f, f3 = f2 * f;
    float omf = 1.0f - f;
    w[0] = omf * omf * omf * (1.0f / 6.0f);
    w[1] = (3.0f * f3 - 6.0f * f2 + 4.0f) * (1.0f / 6.0f);
    w[2] = (-3.0f * f3 + 3.0f * f2 + 3.0f * f + 1.0f) * (1.0f / 6.0f);
    w[3] = f3 * (1.0f / 6.0f);
    dw[0] = -0.5f * omf * omf;
    dw[1] = 1.5f * f2 - 2.0f * f;
    dw[2] = -1.5f * f2 + f + 0.5f;
    dw[3] = 0.5f * f2;
}

__device__ __forceinline__ void atom_base(const float* __restrict__ pos, const float* inv,
                                          int i, int base[3], float fpart[3]) {
    float p0 = pos[3 * i], p1 = pos[3 * i + 1], p2 = pos[3 * i + 2];
#pragma unroll
    for (int d = 0; d < 3; d++) {
        float fr = p0 * inv[d] + p1 * inv[3 + d] + p2 * inv[6 + d];
        fr -= floorf(fr);
        float u = fr * (float)KDIM;
        float bs = floorf(u);
        fpart[d] = u - bs;
        int b = (int)bs;
        base[d] = b & (KDIM - 1);
    }
}

__device__ __forceinline__ float bmod2f(int x) {
    float th = (TWO_PI_F / (float)KDIM) * (float)x;
    float s1, c1, s2, c2;
    __sincosf(th, &s1, &c1);
    __sincosf(th + th, &s2, &c2);
    float dr = 0.16666667f + 0.66666667f * c1 + 0.16666667f * c2;
    float di = 0.66666667f * s1 + 0.16666667f * s2;
    float d2 = dr * dr + di * di;
    return 1.0f / fmaxf(d2, 1e-12f);
}

// ------ zero counts + scrambled tables + twiddle tables, fused ------
// Twiddles computed with the EXACT expression used previously (sign*(PI_F/m)*pos,
// __sincosf) -> FFT results bit-identical.
__global__ __launch_bounds__(256) void zero_tbl_kernel(int* __restrict__ counts,
                                                       float* __restrict__ mtblS,
                                                       float* __restrict__ btblS,
                                                       float2* __restrict__ twF,
                                                       float2* __restrict__ twB) {
    int i = blockIdx.x * 256 + threadIdx.x;
    if (i < NBINS) counts[i] = 0;
    if (blockIdx.x == 0 && threadIdx.x < KDIM) {
        int r = brev7(threadIdx.x);
        mtblS[threadIdx.x] = (float)(r < 64 ? r : r - 128);
        btblS[threadIdx.x] = bmod2f(r);
    }
    if (blockIdx.x == 1) {
        for (int t = threadIdx.x; t < 448; t += 256) {
            int stage = t >> 6, pos = t & 63;
            int m = 1 << stage;
            if (pos < m) {
                float sn, cs;
                float angF = -1.0f * (PI_F / (float)m) * (float)pos;
                __sincosf(angF, &sn, &cs);
                twF[(stage << 6) | pos] = make_float2(cs, sn);
                float angB = 1.0f * (PI_F / (float)m) * (float)pos;
                __sincosf(angB, &sn, &cs);
                twB[(stage << 6) | pos] = make_float2(cs, sn);
            }
        }
    }
}

// ------- binning: histogram (saves per-atom offset) + per-block sum(q^2) -------
__global__ __launch_bounds__(256) void hist_kernel(const float* __restrict__ pos,
                                                   const float* __restrict__ chg,
                                                   const float* __restrict__ cell,
                                                   int* __restrict__ counts,
                                                   int* __restrict__ aoff,
                                                   float* __restrict__ q2_part, int n) {
    __shared__ float hred[4];
    int i = blockIdx.x * blockDim.x + threadIdx.x;
    float q2 = 0.0f;
    if (i < n) {
        float inv[9], det;
        inv3x3(cell, inv, &det);
        int base[3];
        float fp[3];
        atom_base(pos, inv, i, base, fp);
        int bid = ((base[0] >> 3) << 8) | ((base[1] >> 3) << 4) | (base[2] >> 3);
        aoff[i] = atomicAdd(&counts[bid], 1);
        float qi = chg[i];
        q2 = qi * qi;
    }
#pragma unroll
    for (int off = 32; off; off >>= 1) q2 += __shfl_down(q2, off);
    if ((threadIdx.x & 63) == 0) hred[threadIdx.x >> 6] = q2;
    __syncthreads();
    if (threadIdx.x == 0) q2_part[blockIdx.x] = hred[0] + hred[1] + hred[2] + hred[3];
}

__global__ __launch_bounds__(256) void scan_kernel(const int* __restrict__ counts,
                                                   int* __restrict__ starts) {
    __shared__ int part[256];
    int tid = threadIdx.x;
    int local[NBINS / 256];
    int sum = 0;
#pragma unroll
    for (int k = 0; k < NBINS / 256; k++) {
        local[k] = counts[tid * (NBINS / 256) + k];
        sum += local[k];
    }
    part[tid] = sum;
    __syncthreads();
    if (tid == 0) {
        int acc = 0;
        for (int i = 0; i < 256; i++) {
            int t = part[i];
            part[i] = acc;
            acc += t;
        }
        starts[NBINS] = acc;
    }
    __syncthreads();
    int acc = part[tid];
#pragma unroll
    for (int k = 0; k < NBINS / 256; k++) {
        starts[tid * (NBINS / 256) + k] = acc;
        acc += local[k];
    }
}

// scatter (atomic-free): slot = starts[bid] + aoff[i]
// record 32B: rec0 = (fp0, fp1, fp2, q), rec1 = (packed base b0|b1<<7|b2<<14, atom id, 0, 0)
__global__ __launch_bounds__(256) void scatter_kernel(const float* __restrict__ pos,
                                                      const float* __restrict__ chg,
                                                      const float* __restrict__ cell,
                                                      const int* __restrict__ starts,
                                                      const int* __restrict__ aoff,
                                                      float* __restrict__ records, int n) {
    int i = blockIdx.x * blockDim.x + threadIdx.x;
    if (i >= n) return;
    float inv[9], det;
    inv3x3(cell, inv, &det);
    int base[3];
    float fp[3];
    atom_base(pos, inv, i, base, fp);
    int bid = ((base[0] >> 3) << 8) | ((base[1] >> 3) << 4) | (base[2] >> 3);
    int slot = starts[bid] + aoff[i];
    int packed = base[0] | (base[1] << 7) | (base[2] << 14);
    float4* rec = (float4*)(records + (size_t)slot * 8);
    rec[0] = make_float4(fp[0], fp[1], fp[2], chg[i]);
    rec[1] = make_float4(__int_as_float(packed), __int_as_float(i), 0.0f, 0.0f);
}

// ------- spreading: per-wave PRIVATE tiles, NON-ATOMIC read+add+write ----------------
__global__ __launch_bounds__(256) void spread_bins_kernel(
    const float* __restrict__ records, const int* __restrict__ starts,
    float* __restrict__ tiles) {
    __shared__ float tile4[4 * TPAD];
    __shared__ float4 arec[CHUNK * 4];
    int tid = threadIdx.x;
    int bid = blockIdx.x;
    for (int i = tid; i < 4 * TPAD; i += 256) tile4[i] = 0.0f;
    int s = starts[bid], e = starts[bid + 1];
    int w = tid >> 6, l = tid & 63;
    int j0 = l >> 4, j1 = (l >> 2) & 3, j2 = l & 3;
    int joff = j0 * T2 + j1 * TILE_D + j2;
    float* mytile = tile4 + w * TPAD;
    for (int c0 = s; c0 < e; c0 += CHUNK) {
        int cnt = min(CHUNK, e - c0);
        __syncthreads();
        if (tid < cnt) {
            const float4* rp = (const float4*)records + (size_t)(c0 + tid) * 2;
            float4 r0 = rp[0];
            float4 r1 = rp[1];
            float wv[4], dv[4];
            bspline4(r0.x, wv, dv);
            arec[tid * 4 + 0] =
                make_float4(r0.w * wv[0], r0.w * wv[1], r0.w * wv[2], r0.w * wv[3]);
            bspline4(r0.y, wv, dv);
            arec[tid * 4 + 1] = make_float4(wv[0], wv[1], wv[2], wv[3]);
            bspline4(r0.z, wv, dv);
            arec[tid * 4 + 2] = make_float4(wv[0], wv[1], wv[2], wv[3]);
            arec[tid * 4 + 3] = r1;   // packed base in .x
        }
        __syncthreads();
        for (int a = w; a < cnt; a += 4) {
            const float* A = (const float*)&arec[a << 2];
            float val = A[j0] * A[4 + j1] * A[8 + j2];
            int lc = __float_as_int(A[12]);
            int tb = (lc & 7) * T2 + ((lc >> 7) & 7) * TILE_D + ((lc >> 14) & 7);
            mytile[tb + joff] += val;
        }
    }
    __syncthreads();
    float* tout = tiles + (size_t)bid * TSTRIDE;
    for (int i = tid; i < TILE_N; i += 256)
        tout[i] = tile4[i] + tile4[TPAD + i] + tile4[2 * TPAD + i] + tile4[3 * TPAD + i];
}

// ---------------- wave FFTs (table-driven twiddles, bit-identical) ----------------
__device__ __forceinline__ float2 cmul(float2 a, float cs, float sn) {
    return make_float2(a.x * cs - a.y * sn, a.x * sn + a.y * cs);
}

// DIF: natural in -> scrambled out. tw = twF (fwd) or twB (inv).
__device__ __forceinline__ void wave_fft128_dif(float2& v0, float2& v1, int l,
                                                const float2* __restrict__ tw) {
    {
        float2 t = tw[(6 << 6) | l];
        float cs = t.x, sn = t.y;
        float2 d = make_float2(v0.x - v1.x, v0.y - v1.y);
        v0 = make_float2(v0.x + v1.x, v0.y + v1.y);
        v1 = cmul(d, cs, sn);
    }
#pragma unroll
    for (int m = 32; m >= 1; m >>= 1) {
        int stage = __builtin_ctz(m);
        float2 t = tw[(stage << 6) | (l & (m - 1))];
        float cs = t.x, sn = t.y;
        bool hi = (l & m) != 0;
        float2 p0, p1;
        p0.x = __shfl_xor(v0.x, m);
        p0.y = __shfl_xor(v0.y, m);
        p1.x = __shfl_xor(v1.x, m);
        p1.y = __shfl_xor(v1.y, m);
        float2 a0 = hi ? cmul(make_float2(p0.x - v0.x, p0.y - v0.y), cs, sn)
                       : make_float2(v0.x + p0.x, v0.y + p0.y);
        float2 a1 = hi ? cmul(make_float2(p1.x - v1.x, p1.y - v1.y), cs, sn)
                       : make_float2(v1.x + p1.x, v1.y + p1.y);
        v0 = a0;
        v1 = a1;
    }
}

// DIT: brev in -> natural out. tw = twF (fwd) or twB (inv).
__device__ __forceinline__ void wave_fft128_dit(float2& v0, float2& v1, int l,
                                                const float2* __restrict__ tw) {
#pragma unroll
    for (int m = 1; m <= 32; m <<= 1) {
        int stage = __builtin_ctz(m);
        float2 p0, p1;
        p0.x = __shfl_xor(v0.x, m);
        p0.y = __shfl_xor(v0.y, m);
        p1.x = __shfl_xor(v1.x, m);
        p1.y = __shfl_xor(v1.y, m);
        float2 t = tw[(stage << 6) | (l & (m - 1))];
        float cs = t.x, sn = t.y;
        bool hi = (l & m) != 0;
        float2 o0 = hi ? v0 : p0, e0 = hi ? p0 : v0;
        float2 o1 = hi ? v1 : p1, e1 = hi ? p1 : v1;
        float2 t0 = cmul(o0, cs, sn);
        float2 t1 = cmul(o1, cs, sn);
        float s = hi ? -1.0f : 1.0f;
        v0 = make_float2(e0.x + s * t0.x, e0.y + s * t0.y);
        v1 = make_float2(e1.x + s * t1.x, e1.y + s * t1.y);
    }
    float2 t = tw[(6 << 6) | l];
    float cs = t.x, sn = t.y;
    float2 tt = cmul(v1, cs, sn);
    float2 e = v0;
    v0 = make_float2(e.x + tt.x, e.y + tt.y);
    v1 = make_float2(e.x - tt.x, e.y - tt.y);
}

// tile-merge value at mesh point (gx, gy, gz)
__device__ __forceinline__ float merge_val(const float* __restrict__ tiles, int nx, int ny,
                                           const int* bxs, const int* lxs, const int* bys,
                                           const int* lys, int gz) {
    int bz = gz >> 3, oz = gz & 7;
    int nz = (oz >= 5) ? 2 : 1;
    int bzs[2] = {bz, (bz + 1) & 15}, lzs[2] = {oz + 3, oz - 5};
    float v = 0.0f;
    for (int i = 0; i < nx; i++)
        for (int j = 0; j < ny; j++) {
            int bxy = (bxs[i] << 8) | (bys[j] << 4);
            int lo = lxs[i] * T2 + lys[j] * TILE_D;
            for (int k = 0; k < nz; k++)
                v += tiles[(size_t)(bxy | bzs[k]) * TSTRIDE + lo + lzs[k]];
        }
    return v;
}

// ---- fwd-z: tile merge + DIT (natural z out) -> z-major C_t[s][x*128+y], s<=64 only --
__global__ __launch_bounds__(512) void fft_z_merge(const float* __restrict__ tiles,
                                                   float2* __restrict__ C_t,
                                                   const float2* __restrict__ twF) {
    __shared__ float tr[128 * 9], ti[128 * 9];
    int blk = ((blockIdx.x & 7) << 8) | (blockIdx.x >> 3);
    int w = threadIdx.x >> 6, l = threadIdx.x & 63;
    int line = (blk << 3) + w;
    int gx = line >> 7, gy = line & 127;
    int bx = gx >> 3, ox = gx & 7;
    int by = gy >> 3, oy = gy & 7;
    int nx = (ox >= 5) ? 2 : 1, ny = (oy >= 5) ? 2 : 1;
    int bxs[2] = {bx, (bx + 1) & 15}, lxs[2] = {ox + 3, ox - 5};
    int bys[2] = {by, (by + 1) & 15}, lys[2] = {oy + 3, oy - 5};
    float m0 = merge_val(tiles, nx, ny, bxs, lxs, bys, lys, l);
    float m1 = merge_val(tiles, nx, ny, bxs, lxs, bys, lys, l + 64);
    tr[l * 9 + w] = m0;
    ti[l * 9 + w] = 0.0f;
    tr[(l + 64) * 9 + w] = m1;
    ti[(l + 64) * 9 + w] = 0.0f;
    int r = brev7(l);
    float2 v0 = make_float2(tr[r * 9 + w], 0.0f);
    float2 v1 = make_float2(tr[(r + 1) * 9 + w], 0.0f);
    wave_fft128_dit(v0, v1, l, twF);   // forward, natural out
    tr[l * 9 + w] = v0.x;
    ti[l * 9 + w] = v0.y;
    tr[(l + 64) * 9 + w] = v1.x;
    ti[(l + 64) * 9 + w] = v1.y;
    __syncthreads();
    int xy0 = blk << 3;
#pragma unroll
    for (int k = 0; k < 2; k++) {
        int e = threadIdx.x + (k << 9);
        int ss = e >> 3, wl = e & 7;
        if (ss < NZKEEP)
            C_t[(size_t)ss * (KDIM * KDIM) + xy0 + wl] =
                make_float2(tr[ss * 9 + wl], ti[ss * 9 + wl]);
    }
}

// ---- y FFT: contiguous lines in z-major planes (s<=64). DIF=1 fwd, 0 = inv DIT. ----
template <int DIF>
__global__ __launch_bounds__(512) void fft_y(float2* __restrict__ C_t,
                                             const float2* __restrict__ tw) {
    int w = threadIdx.x >> 6, l = threadIdx.x & 63;
    int line = (blockIdx.x << 3) + w;    // line = s*128 + x
    int base = line << 7;
    float2 v0, v1;
    if (DIF) {
        v0 = C_t[base + l];
        v1 = C_t[base + l + 64];
        wave_fft128_dif(v0, v1, l, tw);
    } else {
        int r = brev7(l);
        float4 f = ((const float4*)C_t)[(line << 6) + (r >> 1)];
        v0 = make_float2(f.x, f.y);
        v1 = make_float2(f.z, f.w);
        wave_fft128_dit(v0, v1, l, tw);
    }
    C_t[base + l] = v0;
    C_t[base + l + 64] = v1;
}

// ---- fused: fwd-x DIF + scale + energy + inv-x DIT, strided x within plane s ----
__global__ __launch_bounds__(512) void fft_x_scale(float2* __restrict__ C_t,
                                                   const float* __restrict__ cell,
                                                   const float* __restrict__ mtblS,
                                                   const float* __restrict__ btblS,
                                                   const float2* __restrict__ twF,
                                                   const float2* __restrict__ twB,
                                                   float* __restrict__ scale_part) {
    __shared__ float2 lds[128 * ST];
    __shared__ float red[8];
    int tid = threadIdx.x;
    int s = blockIdx.x >> 3;            // natural z plane, 0..64
    int y0 = (blockIdx.x & 7) << 4;     // y chunk
    int base = s * (KDIM * KDIM) + y0;
#pragma unroll
    for (int k = 0; k < 2; k++) {
        int e = tid + (k << 9);
        int ll = e >> 3, zq = e & 7;
        float4 f = ((const float4*)C_t)[(base >> 1) + ll * 64 + zq];
        lds[ll * ST + 2 * zq] = make_float2(f.x, f.y);
        lds[ll * ST + 2 * zq + 1] = make_float2(f.z, f.w);
    }
    __syncthreads();
    int w = tid >> 6, l = tid & 63;
    float inv[9], det;
    inv3x3(cell, inv, &det);
    float mz = (s == 64) ? -64.0f : (float)s;
    float bz = bmod2f(s);
    float wz = (s == 0 || s == 64) ? 1.0f : 2.0f;
    float contrib = 0.0f;
#pragma unroll
    for (int c = 0; c < 2; c++) {
        int zt = (w << 1) | c;
        float2 v0 = lds[l * ST + zt];
        float2 v1 = lds[(l + 64) * ST + zt];
        wave_fft128_dif(v0, v1, l, twF);
        int yp = y0 + zt;
        float my = mtblS[yp];
        float byz = btblS[yp] * bz;
#pragma unroll
        for (int h = 0; h < 2; h++) {
            int xs = l + (h << 6);
            float mx = mtblS[xs];
            float kx = TWO_PI_F * (mx * inv[0] + my * inv[1] + mz * inv[2]);
            float ky = TWO_PI_F * (mx * inv[3] + my * inv[4] + mz * inv[5]);
            float kz = TWO_PI_F * (mx * inv[6] + my * inv[7] + mz * inv[8]);
            float k2 = kx * kx + ky * ky + kz * kz;
            float A = 0.0f;
            if (k2 > 0.0f)
                A = __expf(-k2 / (4.0f * ALPHA_F * ALPHA_F)) / k2 * btblS[xs] * byz;
            float2& v = h ? v1 : v0;
            contrib += A * (v.x * v.x + v.y * v.y);
            v.x *= A;
            v.y *= A;
        }
        wave_fft128_dit(v0, v1, l, twB);
        lds[l * ST + zt] = v0;
        lds[(l + 64) * ST + zt] = v1;
    }
    contrib *= wz;
#pragma unroll
    for (int off = 32; off; off >>= 1) contrib += __shfl_down(contrib, off);
    if (l == 0) red[w] = contrib;
    __syncthreads();
    if (tid == 0) {
        float v = 0.0f;
        for (int i = 0; i < 8; i++) v += red[i];
        scale_part[blockIdx.x] = v;
    }
#pragma unroll
    for (int k = 0; k < 2; k++) {
        int e = tid + (k << 9);
        int ll = e >> 3, zq = e & 7;
        float2 a = lds[ll * ST + 2 * zq];
        float2 b = lds[ll * ST + 2 * zq + 1];
        ((float4*)C_t)[(base >> 1) + ll * 64 + zq] = make_float4(a.x, a.y, b.x, b.y);
    }
}

// ---- inv-z: Hermitian reconstruction + DIT -> phi[xy][z] ----
__global__ __launch_bounds__(512) void fft_z_phi(const float2* __restrict__ C_t,
                                                 const float2* __restrict__ twB,
                                                 float* __restrict__ phi) {
    __shared__ float tr[NZKEEP * ZST], ti[NZKEEP * ZST];
    int tid = threadIdx.x;
    int xy0 = blockIdx.x << 4;   // 16 xy lines per block
    for (int e = tid; e < NZKEEP * 16; e += 512) {
        int ss = e >> 4, q = e & 15;
        float2 v = C_t[(size_t)ss * (KDIM * KDIM) + xy0 + q];
        tr[ss * ZST + q] = v.x;
        ti[ss * ZST + q] = v.y;
    }
    __syncthreads();
    int w = tid >> 6, l = tid & 63;
    int r = brev7(l);   // even, 0..126
#pragma unroll
    for (int c0 = 0; c0 < 2; c0++) {
        int c = (w << 1) | c0;
        float2 v0, v1;
        if (r <= 62) {
            v0 = make_float2(tr[r * ZST + c], ti[r * ZST + c]);
            v1 = make_float2(tr[(r + 1) * ZST + c], ti[(r + 1) * ZST + c]);
        } else if (r == 64) {
            v0 = make_float2(tr[64 * ZST + c], ti[64 * ZST + c]);
            v1 = make_float2(tr[63 * ZST + c], -ti[63 * ZST + c]);
        } else {
            int m0 = 128 - r;   // 2..62
            v0 = make_float2(tr[m0 * ZST + c], -ti[m0 * ZST + c]);
            v1 = make_float2(tr[(m0 - 1) * ZST + c], -ti[(m0 - 1) * ZST + c]);
        }
        wave_fft128_dit(v0, v1, l, twB);
        phi[(xy0 + c) * KDIM + l] = v0.x;
        phi[(xy0 + c) * KDIM + l + 64] = v1.x;
    }
}

// ------- force gather (record-driven) + fused energy finalize in block 0 ------
__global__ __launch_bounds__(256) void gather_kernel(
    const float* __restrict__ records, const float* __restrict__ cell,
    const float* __restrict__ phi, const float* __restrict__ scale_part,
    const float* __restrict__ q2_part, int nq2, float* __restrict__ out, int n) {
    __shared__ double sd[256];
    if (blockIdx.x == 0) {
        int tid = threadIdx.x;
        double es = 0.0;
        for (int i = tid; i < NSCALE_BLK; i += 256) es += (double)scale_part[i];
        double q2 = 0.0;
        for (int i = tid; i < nq2; i += 256) q2 += (double)q2_part[i];
        sd[tid] = es;
        __syncthreads();
        for (int s = 128; s; s >>= 1) {
            if (tid < s) sd[tid] += sd[tid + s];
            __syncthreads();
        }
        double esum = sd[0];
        __syncthreads();
        sd[tid] = q2;
        __syncthreads();
        for (int s = 128; s; s >>= 1) {
            if (tid < s) sd[tid] += sd[tid + s];
            __syncthreads();
        }
        if (tid == 0) {
            float invf[9], det;
            inv3x3(cell, invf, &det);
            double cc = (double)KE_F * 2.0 * 3.14159265358979323846 / (double)det;
            double e = cc * esum -
                       (double)KE_F * (double)ALPHA_F / 1.7724538509055160273 * sd[0];
            out[0] = (float)e;
        }
    }
    int a = blockIdx.x * blockDim.x + threadIdx.x;
    if (a >= n) return;
    const float4* rec = (const float4*)(records + (size_t)a * 8);
    float4 r0 = rec[0];
    float4 r1 = rec[1];
    int packed = __float_as_int(r1.x);
    int i = __float_as_int(r1.y);
    int b0 = packed & 127, b1 = (packed >> 7) & 127, bz = (packed >> 14) & 127;
    float inv[9], det;
    inv3x3(cell, inv, &det);
    float wx[4], wy[4], wzv[4], dxv[4], dyv[4], dzv[4];
    bspline4(r0.x, wx, dxv);
    bspline4(r0.y, wy, dyv);
    bspline4(r0.z, wzv, dzv);
    int ix[4], iy[4];
#pragma unroll
    for (int j = 0; j < 4; j++) {
        ix[j] = (b0 - 3 + j + KDIM) & (KDIM - 1);
        iy[j] = (b1 - 3 + j + KDIM) & (KDIM - 1);
    }
    float acc0 = 0.0f, acc1 = 0.0f, acc2 = 0.0f;
    if (bz >= 3) {
        int z0 = bz - 3;
#pragma unroll
        for (int j0 = 0; j0 < 4; j0++) {
            int r0i = ix[j0] << 14;
            float wxx = wx[j0], dxx = dxv[j0];
#pragma unroll
            for (int j1 = 0; j1 < 4; j1++) {
                pf4 p = ld4u(&phi[r0i + (iy[j1] << 7) + z0]);
                float sw = p.a * wzv[0] + p.b * wzv[1] + p.c * wzv[2] + p.d * wzv[3];
                float sdz = p.a * dzv[0] + p.b * dzv[1] + p.c * dzv[2] + p.d * dzv[3];
                float wyy = wy[j1];
                acc0 += sw * dxx * wyy;
                acc1 += sw * wxx * dyv[j1];
                acc2 += sdz * wxx * wyy;
            }
        }
    } else {
        int iz[4];
#pragma unroll
        for (int j = 0; j < 4; j++) iz[j] = (bz - 3 + j + KDIM) & (KDIM - 1);
#pragma unroll
        for (int j0 = 0; j0 < 4; j0++) {
            int r0i = ix[j0] << 14;
            float wxx = wx[j0], dxx = dxv[j0];
#pragma unroll
            for (int j1 = 0; j1 < 4; j1++) {
                int r1i = r0i + (iy[j1] << 7);
                float sw = 0.0f, sdz = 0.0f;
#pragma unroll
                for (int j2 = 0; j2 < 4; j2++) {
                    float p = phi[r1i + iz[j2]];
                    sw += p * wzv[j2];
                    sdz += p * dzv[j2];
                }
                float wyy = wy[j1];
                acc0 += sw * dxx * wyy;
                acc1 += sw * wxx * dyv[j1];
                acc2 += sdz * wxx * wyy;
            }
        }
    }
    float qi = r0.w;
    float c = KE_F * TWO_PI_F / det;
    float fac = -2.0f * c * qi * (float)KDIM;
    out[1 + 3 * i + 0] = fac * (acc0 * inv[0] + acc1 * inv[1] + acc2 * inv[2]);
    out[1 + 3 * i + 1] = fac * (acc0 * inv[3] + acc1 * inv[4] + acc2 * inv[5]);
    out[1 + 3 * i + 2] = fac * (acc0 * inv[6] + acc1 * inv[7] + acc2 * inv[8]);
}

extern "C" void kernel_launch(void* const* d_in, const int* in_sizes, int n_in,
                              void* d_out, int out_size, void* d_ws, size_t ws_size,
                              hipStream_t stream) {
    const float* pos = (const float*)d_in[0];
    const float* chg = (const float*)d_in[1];
    const float* cell = (const float*)d_in[2];
    float* out = (float*)d_out;
    int n = in_sizes[1];
    int nb = (n + 255) / 256;

    char* w = (char*)d_ws;
    float2* C_t = (float2*)w;                     // NTOT float2; FFT uses planes 0..64
    size_t off = (size_t)NTOT * sizeof(float2);
    float* tiles = (float*)(w + off);             // 22.02 MB; phi aliases this
    off += (size_t)NBINS * TSTRIDE * sizeof(float);
    int* counts = (int*)(w + off);                // NBINS
    off += NBINS * sizeof(int);
    int* starts = (int*)(w + off);                // NBINS+1
    off += (NBINS + 1) * sizeof(int);
    int* aoff = (int*)(w + off);                  // n
    off += (size_t)n * sizeof(int);
    float* scale_part = (float*)(w + off);        // NSCALE_BLK
    off += NSCALE_BLK * sizeof(float);
    float* q2_part = (float*)(w + off);           // nb
    off += (size_t)nb * sizeof(float);
    float* mtblS = (float*)(w + off);             // 128
    off += KDIM * sizeof(float);
    float* btblS = (float*)(w + off);             // 128
    off += KDIM * sizeof(float);
    float2* twF = (float2*)(w + off);             // 448 float2
    off += 448 * sizeof(float2);
    float2* twB = (float2*)(w + off);             // 448 float2

    // records live in C_t's dead upper region (planes 65..127 never touched by FFT)
    float* records = (float*)(C_t + (size_t)NZKEEP * KDIM * KDIM);
    float* phi = (float*)tiles;                   // tiles dead after fft_z_merge

    zero_tbl_kernel<<<(NBINS + 255) / 256, 256, 0, stream>>>(counts, mtblS, btblS, twF,
                                                             twB);
    hist_kernel<<<nb, 256, 0, stream>>>(pos, chg, cell, counts, aoff, q2_part, n);
    scan_kernel<<<1, 256, 0, stream>>>(counts, starts);
    scatter_kernel<<<nb, 256, 0, stream>>>(pos, chg, cell, starts, aoff, records, n);
    spread_bins_kernel<<<NBINS, 256, 0, stream>>>(records, starts, tiles);

    fft_z_merge<<<2048, 512, 0, stream>>>(tiles, C_t, twF);     // fwd z, natural, s<=64
    fft_y<1><<<NZKEEP * KDIM / 8, 512, 0, stream>>>(C_t, twF);  // fwd y (contiguous)
    fft_x_scale<<<NSCALE_BLK, 512, 0, stream>>>(C_t, cell, mtblS, btblS, twF, twB,
                                                scale_part);
    fft_y<0><<<NZKEEP * KDIM / 8, 512, 0, stream>>>(C_t, twB);  // inv y (contiguous)
    fft_z_phi<<<KDIM * KDIM / 16, 512, 0, stream>>>(C_t, twB, phi);  // inv z + Hermitian

    gather_kernel<<<nb, 256, 0, stream>>>(records, cell, phi, scale_part, q2_part, nb,
                                          out, n);
}

// Round 19
// 124.268 us; speedup vs baseline: 1.0347x; 1.0347x over previous
//
#include <hip/hip_runtime.h>

#define KDIM 128
#define NTOT (KDIM * KDIM * KDIM)
#define BPD 16          // bins per dim
#define NBINS (BPD * BPD * BPD)
#define TILE_D 11       // 8 + 3 halo
#define T2 (TILE_D * TILE_D)
#define TILE_N (TILE_D * TILE_D * TILE_D)
#define TPAD 1332       // per-wave LDS tile stride (floats)
#define TSTRIDE 1344    // padded global tile stride (floats)
#define CHUNK 256
#define NZKEEP 65       // Hermitian: keep z-planes 0..64
#define NSCALE_BLK (NZKEEP * 8)
#define ST 17           // LDS row stride (float2) for x transpose stage
#define ZST 17          // z-phi LDS row stride (floats)

static constexpr float PI_F = 3.14159265358979323846f;
static constexpr float TWO_PI_F = 6.28318530717958647692f;
static constexpr float KE_F = 14.3996f;
static constexpr float ALPHA_F = 0.35f;

__device__ __forceinline__ int brev7(int i) { return (int)(__brev((unsigned)i) >> 25); }

struct pf4 { float a, b, c, d; };
__device__ __forceinline__ pf4 ld4u(const float* p) {
    pf4 v;
    __builtin_memcpy(&v, p, 16);
    return v;
}

__device__ __forceinline__ void inv3x3(const float* c, float* inv, float* adet) {
    float a00 = c[0], a01 = c[1], a02 = c[2];
    float a10 = c[3], a11 = c[4], a12 = c[5];
    float a20 = c[6], a21 = c[7], a22 = c[8];
    float det = a00 * (a11 * a22 - a12 * a21) - a01 * (a10 * a22 - a12 * a20) +
                a02 * (a10 * a21 - a11 * a20);
    float id = 1.0f / det;
    inv[0] = (a11 * a22 - a12 * a21) * id;
    inv[1] = (a02 * a21 - a01 * a22) * id;
    inv[2] = (a01 * a12 - a02 * a11) * id;
    inv[3] = (a12 * a20 - a10 * a22) * id;
    inv[4] = (a00 * a22 - a02 * a20) * id;
    inv[5] = (a02 * a10 - a00 * a12) * id;
    inv[6] = (a10 * a21 - a11 * a20) * id;
    inv[7] = (a01 * a20 - a00 * a21) * id;
    inv[8] = (a00 * a11 - a01 * a10) * id;
    *adet = fabsf(det);
}

__device__ __forceinline__ void bspline4(float f, float* w, float* dw) {
    float f2 = f * f, f3 = f2 * f;
    float omf = 1.0f - f;
    w[0] = omf * omf * omf * (1.0f / 6.0f);
    w[1] = (3.0f * f3 - 6.0f * f2 + 4.0f) * (1.0f / 6.0f);
    w[2] = (-3.0f * f3 + 3.0f * f2 + 3.0f * f + 1.0f) * (1.0f / 6.0f);
    w[3] = f3 * (1.0f / 6.0f);
    dw[0] = -0.5f * omf * omf;
    dw[1] = 1.5f * f2 - 2.0f * f;
    dw[2] = -1.5f * f2 + f + 0.5f;
    dw[3] = 0.5f * f2;
}

__device__ __forceinline__ void atom_base(const float* __restrict__ pos, const float* inv,
                                          int i, int base[3], float fpart[3]) {
    float p0 = pos[3 * i], p1 = pos[3 * i + 1], p2 = pos[3 * i + 2];
#pragma unroll
    for (int d = 0; d < 3; d++) {
        float fr = p0 * inv[d] + p1 * inv[3 + d] + p2 * inv[6 + d];
        fr -= floorf(fr);
        float u = fr * (float)KDIM;
        float bs = floorf(u);
        fpart[d] = u - bs;
        int b = (int)bs;
        base[d] = b & (KDIM - 1);
    }
}

__device__ __forceinline__ float bmod2f(int x) {
    float th = (TWO_PI_F / (float)KDIM) * (float)x;
    float s1, c1, s2, c2;
    __sincosf(th, &s1, &c1);
    __sincosf(th + th, &s2, &c2);
    float dr = 0.16666667f + 0.66666667f * c1 + 0.16666667f * c2;
    float di = 0.66666667f * s1 + 0.16666667f * s2;
    float d2 = dr * dr + di * di;
    return 1.0f / fmaxf(d2, 1e-12f);
}

// ------ zero counts + scrambled tables, fused ------
__global__ __launch_bounds__(256) void zero_tbl_kernel(int* __restrict__ counts,
                                                       float* __restrict__ mtblS,
                                                       float* __restrict__ btblS) {
    int i = blockIdx.x * 256 + threadIdx.x;
    if (i < NBINS) counts[i] = 0;
    if (blockIdx.x == 0 && threadIdx.x < KDIM) {
        int r = brev7(threadIdx.x);
        mtblS[threadIdx.x] = (float)(r < 64 ? r : r - 128);
        btblS[threadIdx.x] = bmod2f(r);
    }
}

// ------- binning: histogram (saves per-atom offset) + per-block sum(q^2) -------
__global__ __launch_bounds__(256) void hist_kernel(const float* __restrict__ pos,
                                                   const float* __restrict__ chg,
                                                   const float* __restrict__ cell,
                                                   int* __restrict__ counts,
                                                   int* __restrict__ aoff,
                                                   float* __restrict__ q2_part, int n) {
    __shared__ float hred[4];
    int i = blockIdx.x * blockDim.x + threadIdx.x;
    float q2 = 0.0f;
    if (i < n) {
        float inv[9], det;
        inv3x3(cell, inv, &det);
        int base[3];
        float fp[3];
        atom_base(pos, inv, i, base, fp);
        int bid = ((base[0] >> 3) << 8) | ((base[1] >> 3) << 4) | (base[2] >> 3);
        aoff[i] = atomicAdd(&counts[bid], 1);
        float qi = chg[i];
        q2 = qi * qi;
    }
#pragma unroll
    for (int off = 32; off; off >>= 1) q2 += __shfl_down(q2, off);
    if ((threadIdx.x & 63) == 0) hred[threadIdx.x >> 6] = q2;
    __syncthreads();
    if (threadIdx.x == 0) q2_part[blockIdx.x] = hred[0] + hred[1] + hred[2] + hred[3];
}

__global__ __launch_bounds__(256) void scan_kernel(const int* __restrict__ counts,
                                                   int* __restrict__ starts) {
    __shared__ int part[256];
    int tid = threadIdx.x;
    int local[NBINS / 256];
    int sum = 0;
#pragma unroll
    for (int k = 0; k < NBINS / 256; k++) {
        local[k] = counts[tid * (NBINS / 256) + k];
        sum += local[k];
    }
    part[tid] = sum;
    __syncthreads();
    if (tid == 0) {
        int acc = 0;
        for (int i = 0; i < 256; i++) {
            int t = part[i];
            part[i] = acc;
            acc += t;
        }
        starts[NBINS] = acc;
    }
    __syncthreads();
    int acc = part[tid];
#pragma unroll
    for (int k = 0; k < NBINS / 256; k++) {
        starts[tid * (NBINS / 256) + k] = acc;
        acc += local[k];
    }
}

// scatter (atomic-free): slot = starts[bid] + aoff[i]
// record 32B: rec0 = (fp0, fp1, fp2, q), rec1 = (packed base b0|b1<<7|b2<<14, atom id, 0, 0)
__global__ __launch_bounds__(256) void scatter_kernel(const float* __restrict__ pos,
                                                      const float* __restrict__ chg,
                                                      const float* __restrict__ cell,
                                                      const int* __restrict__ starts,
                                                      const int* __restrict__ aoff,
                                                      float* __restrict__ records, int n) {
    int i = blockIdx.x * blockDim.x + threadIdx.x;
    if (i >= n) return;
    float inv[9], det;
    inv3x3(cell, inv, &det);
    int base[3];
    float fp[3];
    atom_base(pos, inv, i, base, fp);
    int bid = ((base[0] >> 3) << 8) | ((base[1] >> 3) << 4) | (base[2] >> 3);
    int slot = starts[bid] + aoff[i];
    int packed = base[0] | (base[1] << 7) | (base[2] << 14);
    float4* rec = (float4*)(records + (size_t)slot * 8);
    rec[0] = make_float4(fp[0], fp[1], fp[2], chg[i]);
    rec[1] = make_float4(__int_as_float(packed), __int_as_float(i), 0.0f, 0.0f);
}

// ------- spreading: per-wave PRIVATE tiles, NON-ATOMIC read+add+write ----------------
__global__ __launch_bounds__(256) void spread_bins_kernel(
    const float* __restrict__ records, const int* __restrict__ starts,
    float* __restrict__ tiles) {
    __shared__ float tile4[4 * TPAD];
    __shared__ float4 arec[CHUNK * 4];
    int tid = threadIdx.x;
    int bid = blockIdx.x;
    for (int i = tid; i < 4 * TPAD; i += 256) tile4[i] = 0.0f;
    int s = starts[bid], e = starts[bid + 1];
    int w = tid >> 6, l = tid & 63;
    int j0 = l >> 4, j1 = (l >> 2) & 3, j2 = l & 3;
    int joff = j0 * T2 + j1 * TILE_D + j2;
    float* mytile = tile4 + w * TPAD;
    for (int c0 = s; c0 < e; c0 += CHUNK) {
        int cnt = min(CHUNK, e - c0);
        __syncthreads();
        if (tid < cnt) {
            const float4* rp = (const float4*)records + (size_t)(c0 + tid) * 2;
            float4 r0 = rp[0];
            float4 r1 = rp[1];
            float wv[4], dv[4];
            bspline4(r0.x, wv, dv);
            arec[tid * 4 + 0] =
                make_float4(r0.w * wv[0], r0.w * wv[1], r0.w * wv[2], r0.w * wv[3]);
            bspline4(r0.y, wv, dv);
            arec[tid * 4 + 1] = make_float4(wv[0], wv[1], wv[2], wv[3]);
            bspline4(r0.z, wv, dv);
            arec[tid * 4 + 2] = make_float4(wv[0], wv[1], wv[2], wv[3]);
            arec[tid * 4 + 3] = r1;   // packed base in .x
        }
        __syncthreads();
        for (int a = w; a < cnt; a += 4) {
            const float* A = (const float*)&arec[a << 2];
            float val = A[j0] * A[4 + j1] * A[8 + j2];
            int lc = __float_as_int(A[12]);
            int tb = (lc & 7) * T2 + ((lc >> 7) & 7) * TILE_D + ((lc >> 14) & 7);
            mytile[tb + joff] += val;
        }
    }
    __syncthreads();
    float* tout = tiles + (size_t)bid * TSTRIDE;
    for (int i = tid; i < TILE_N; i += 256)
        tout[i] = tile4[i] + tile4[TPAD + i] + tile4[2 * TPAD + i] + tile4[3 * TPAD + i];
}

// ---------------- wave FFTs ----------------
__device__ __forceinline__ float2 cmul(float2 a, float cs, float sn) {
    return make_float2(a.x * cs - a.y * sn, a.x * sn + a.y * cs);
}

// DIF: natural in (v0=elem l, v1=elem l+64) -> scrambled out (slots l, l+64)
__device__ __forceinline__ void wave_fft128_dif(float2& v0, float2& v1, int l, float sign) {
    {
        float ang = sign * (PI_F / 64.0f) * (float)l;
        float sn, cs;
        __sincosf(ang, &sn, &cs);
        float2 d = make_float2(v0.x - v1.x, v0.y - v1.y);
        v0 = make_float2(v0.x + v1.x, v0.y + v1.y);
        v1 = cmul(d, cs, sn);
    }
#pragma unroll
    for (int m = 32; m >= 1; m >>= 1) {
        float ang = sign * (PI_F / (float)m) * (float)(l & (m - 1));
        float sn, cs;
        __sincosf(ang, &sn, &cs);
        bool hi = (l & m) != 0;
        float2 p0, p1;
        p0.x = __shfl_xor(v0.x, m);
        p0.y = __shfl_xor(v0.y, m);
        p1.x = __shfl_xor(v1.x, m);
        p1.y = __shfl_xor(v1.y, m);
        float2 a0 = hi ? cmul(make_float2(p0.x - v0.x, p0.y - v0.y), cs, sn)
                       : make_float2(v0.x + p0.x, v0.y + p0.y);
        float2 a1 = hi ? cmul(make_float2(p1.x - v1.x, p1.y - v1.y), cs, sn)
                       : make_float2(v1.x + p1.x, v1.y + p1.y);
        v0 = a0;
        v1 = a1;
    }
}

// DIT: brev in (v0=elem[brev7(l)], v1=elem[brev7(l)+1]) -> natural out (l, l+64)
__device__ __forceinline__ void wave_fft128_dit(float2& v0, float2& v1, int l, float sign) {
#pragma unroll
    for (int m = 1; m <= 32; m <<= 1) {
        float2 p0, p1;
        p0.x = __shfl_xor(v0.x, m);
        p0.y = __shfl_xor(v0.y, m);
        p1.x = __shfl_xor(v1.x, m);
        p1.y = __shfl_xor(v1.y, m);
        float ang = sign * (PI_F / (float)m) * (float)(l & (m - 1));
        float sn, cs;
        __sincosf(ang, &sn, &cs);
        bool hi = (l & m) != 0;
        float2 o0 = hi ? v0 : p0, e0 = hi ? p0 : v0;
        float2 o1 = hi ? v1 : p1, e1 = hi ? p1 : v1;
        float2 t0 = cmul(o0, cs, sn);
        float2 t1 = cmul(o1, cs, sn);
        float s = hi ? -1.0f : 1.0f;
        v0 = make_float2(e0.x + s * t0.x, e0.y + s * t0.y);
        v1 = make_float2(e1.x + s * t1.x, e1.y + s * t1.y);
    }
    float ang = sign * (PI_F / 64.0f) * (float)l;
    float sn, cs;
    __sincosf(ang, &sn, &cs);
    float2 t = cmul(v1, cs, sn);
    float2 e = v0;
    v0 = make_float2(e.x + t.x, e.y + t.y);
    v1 = make_float2(e.x - t.x, e.y - t.y);
}

// tile-merge value at mesh point (gx, gy, gz)
__device__ __forceinline__ float merge_val(const float* __restrict__ tiles, int nx, int ny,
                                           const int* bxs, const int* lxs, const int* bys,
                                           const int* lys, int gz) {
    int bz = gz >> 3, oz = gz & 7;
    int nz = (oz >= 5) ? 2 : 1;
    int bzs[2] = {bz, (bz + 1) & 15}, lzs[2] = {oz + 3, oz - 5};
    float v = 0.0f;
    for (int i = 0; i < nx; i++)
        for (int j = 0; j < ny; j++) {
            int bxy = (bxs[i] << 8) | (bys[j] << 4);
            int lo = lxs[i] * T2 + lys[j] * TILE_D;
            for (int k = 0; k < nz; k++)
                v += tiles[(size_t)(bxy | bzs[k]) * TSTRIDE + lo + lzs[k]];
        }
    return v;
}

// ---- fwd-z: tile merge + DIT (natural z out) -> z-major C_t[s][x*128+y], s<=64 only --
__global__ __launch_bounds__(512) void fft_z_merge(const float* __restrict__ tiles,
                                                   float2* __restrict__ C_t) {
    __shared__ float tr[128 * 9], ti[128 * 9];
    int w = threadIdx.x >> 6, l = threadIdx.x & 63;
    int line = (blockIdx.x << 3) + w;
    int gx = line >> 7, gy = line & 127;
    int bx = gx >> 3, ox = gx & 7;
    int by = gy >> 3, oy = gy & 7;
    int nx = (ox >= 5) ? 2 : 1, ny = (oy >= 5) ? 2 : 1;
    int bxs[2] = {bx, (bx + 1) & 15}, lxs[2] = {ox + 3, ox - 5};
    int bys[2] = {by, (by + 1) & 15}, lys[2] = {oy + 3, oy - 5};
    float m0 = merge_val(tiles, nx, ny, bxs, lxs, bys, lys, l);
    float m1 = merge_val(tiles, nx, ny, bxs, lxs, bys, lys, l + 64);
    tr[l * 9 + w] = m0;
    ti[l * 9 + w] = 0.0f;
    tr[(l + 64) * 9 + w] = m1;
    ti[(l + 64) * 9 + w] = 0.0f;
    int r = brev7(l);
    float2 v0 = make_float2(tr[r * 9 + w], 0.0f);
    float2 v1 = make_float2(tr[(r + 1) * 9 + w], 0.0f);
    wave_fft128_dit(v0, v1, l, -1.0f);   // forward, natural out
    tr[l * 9 + w] = v0.x;
    ti[l * 9 + w] = v0.y;
    tr[(l + 64) * 9 + w] = v1.x;
    ti[(l + 64) * 9 + w] = v1.y;
    __syncthreads();
    int xy0 = blockIdx.x << 3;
#pragma unroll
    for (int k = 0; k < 2; k++) {
        int e = threadIdx.x + (k << 9);
        int ss = e >> 3, wl = e & 7;
        if (ss < NZKEEP)
            C_t[(size_t)ss * (KDIM * KDIM) + xy0 + wl] =
                make_float2(tr[ss * 9 + wl], ti[ss * 9 + wl]);
    }
}

// ---- y FFT: contiguous lines in z-major planes (s<=64). DIF=1 fwd, 0 = inv DIT. ----
template <int DIF>
__global__ __launch_bounds__(512) void fft_y(float2* __restrict__ C_t) {
    int w = threadIdx.x >> 6, l = threadIdx.x & 63;
    int line = (blockIdx.x << 3) + w;    // line = s*128 + x
    int base = line << 7;
    float2 v0, v1;
    if (DIF) {
        v0 = C_t[base + l];
        v1 = C_t[base + l + 64];
        wave_fft128_dif(v0, v1, l, -1.0f);
    } else {
        int r = brev7(l);
        float4 f = ((const float4*)C_t)[(line << 6) + (r >> 1)];
        v0 = make_float2(f.x, f.y);
        v1 = make_float2(f.z, f.w);
        wave_fft128_dit(v0, v1, l, 1.0f);
    }
    C_t[base + l] = v0;
    C_t[base + l + 64] = v1;
}

// ---- fused: fwd-x DIF + scale + energy + inv-x DIT, strided x within plane s ----
__global__ __launch_bounds__(512) void fft_x_scale(float2* __restrict__ C_t,
                                                   const float* __restrict__ cell,
                                                   const float* __restrict__ mtblS,
                                                   const float* __restrict__ btblS,
                                                   float* __restrict__ scale_part) {
    __shared__ float2 lds[128 * ST];
    __shared__ float red[8];
    int tid = threadIdx.x;
    int s = blockIdx.x >> 3;            // natural z plane, 0..64
    int y0 = (blockIdx.x & 7) << 4;     // y chunk
    int base = s * (KDIM * KDIM) + y0;
#pragma unroll
    for (int k = 0; k < 2; k++) {
        int e = tid + (k << 9);
        int ll = e >> 3, zq = e & 7;
        float4 f = ((const float4*)C_t)[(base >> 1) + ll * 64 + zq];
        lds[ll * ST + 2 * zq] = make_float2(f.x, f.y);
        lds[ll * ST + 2 * zq + 1] = make_float2(f.z, f.w);
    }
    __syncthreads();
    int w = tid >> 6, l = tid & 63;
    float inv[9], det;
    inv3x3(cell, inv, &det);
    float mz = (s == 64) ? -64.0f : (float)s;
    float bz = bmod2f(s);
    float wz = (s == 0 || s == 64) ? 1.0f : 2.0f;
    float contrib = 0.0f;
#pragma unroll
    for (int c = 0; c < 2; c++) {
        int zt = (w << 1) | c;
        float2 v0 = lds[l * ST + zt];
        float2 v1 = lds[(l + 64) * ST + zt];
        wave_fft128_dif(v0, v1, l, -1.0f);
        int yp = y0 + zt;
        float my = mtblS[yp];
        float byz = btblS[yp] * bz;
#pragma unroll
        for (int h = 0; h < 2; h++) {
            int xs = l + (h << 6);
            float mx = mtblS[xs];
            float kx = TWO_PI_F * (mx * inv[0] + my * inv[1] + mz * inv[2]);
            float ky = TWO_PI_F * (mx * inv[3] + my * inv[4] + mz * inv[5]);
            float kz = TWO_PI_F * (mx * inv[6] + my * inv[7] + mz * inv[8]);
            float k2 = kx * kx + ky * ky + kz * kz;
            float A = 0.0f;
            if (k2 > 0.0f)
                A = __expf(-k2 / (4.0f * ALPHA_F * ALPHA_F)) / k2 * btblS[xs] * byz;
            float2& v = h ? v1 : v0;
            contrib += A * (v.x * v.x + v.y * v.y);
            v.x *= A;
            v.y *= A;
        }
        wave_fft128_dit(v0, v1, l, 1.0f);
        lds[l * ST + zt] = v0;
        lds[(l + 64) * ST + zt] = v1;
    }
    contrib *= wz;
#pragma unroll
    for (int off = 32; off; off >>= 1) contrib += __shfl_down(contrib, off);
    if (l == 0) red[w] = contrib;
    __syncthreads();
    if (tid == 0) {
        float v = 0.0f;
        for (int i = 0; i < 8; i++) v += red[i];
        scale_part[blockIdx.x] = v;
    }
#pragma unroll
    for (int k = 0; k < 2; k++) {
        int e = tid + (k << 9);
        int ll = e >> 3, zq = e & 7;
        float2 a = lds[ll * ST + 2 * zq];
        float2 b = lds[ll * ST + 2 * zq + 1];
        ((float4*)C_t)[(base >> 1) + ll * 64 + zq] = make_float4(a.x, a.y, b.x, b.y);
    }
}

// ---- inv-z: Hermitian reconstruction + DIT -> phi[xy][z] ----
__global__ __launch_bounds__(512) void fft_z_phi(const float2* __restrict__ C_t,
                                                 float* __restrict__ phi) {
    __shared__ float tr[NZKEEP * ZST], ti[NZKEEP * ZST];
    int tid = threadIdx.x;
    int xy0 = blockIdx.x << 4;   // 16 xy lines per block
    for (int e = tid; e < NZKEEP * 16; e += 512) {
        int ss = e >> 4, q = e & 15;
        float2 v = C_t[(size_t)ss * (KDIM * KDIM) + xy0 + q];
        tr[ss * ZST + q] = v.x;
        ti[ss * ZST + q] = v.y;
    }
    __syncthreads();
    int w = tid >> 6, l = tid & 63;
    int r = brev7(l);   // even, 0..126
#pragma unroll
    for (int c0 = 0; c0 < 2; c0++) {
        int c = (w << 1) | c0;
        float2 v0, v1;
        if (r <= 62) {
            v0 = make_float2(tr[r * ZST + c], ti[r * ZST + c]);
            v1 = make_float2(tr[(r + 1) * ZST + c], ti[(r + 1) * ZST + c]);
        } else if (r == 64) {
            v0 = make_float2(tr[64 * ZST + c], ti[64 * ZST + c]);
            v1 = make_float2(tr[63 * ZST + c], -ti[63 * ZST + c]);
        } else {
            int m0 = 128 - r;   // 2..62
            v0 = make_float2(tr[m0 * ZST + c], -ti[m0 * ZST + c]);
            v1 = make_float2(tr[(m0 - 1) * ZST + c], -ti[(m0 - 1) * ZST + c]);
        }
        wave_fft128_dit(v0, v1, l, 1.0f);
        phi[(xy0 + c) * KDIM + l] = v0.x;
        phi[(xy0 + c) * KDIM + l + 64] = v1.x;
    }
}

// ------- force gather (record-driven, coalesced) + fused energy finalize in block 0 --
__global__ __launch_bounds__(256) void gather_kernel(
    const float* __restrict__ records, const float* __restrict__ cell,
    const float* __restrict__ phi, const float* __restrict__ scale_part,
    const float* __restrict__ q2_part, int nq2, float* __restrict__ out, int n) {
    __shared__ double sd[256];
    if (blockIdx.x == 0) {
        int tid = threadIdx.x;
        double es = 0.0;
        for (int i = tid; i < NSCALE_BLK; i += 256) es += (double)scale_part[i];
        double q2 = 0.0;
        for (int i = tid; i < nq2; i += 256) q2 += (double)q2_part[i];
        sd[tid] = es;
        __syncthreads();
        for (int s = 128; s; s >>= 1) {
            if (tid < s) sd[tid] += sd[tid + s];
            __syncthreads();
        }
        double esum = sd[0];
        __syncthreads();
        sd[tid] = q2;
        __syncthreads();
        for (int s = 128; s; s >>= 1) {
            if (tid < s) sd[tid] += sd[tid + s];
            __syncthreads();
        }
        if (tid == 0) {
            float invf[9], det;
            inv3x3(cell, invf, &det);
            double cc = (double)KE_F * 2.0 * 3.14159265358979323846 / (double)det;
            double e = cc * esum -
                       (double)KE_F * (double)ALPHA_F / 1.7724538509055160273 * sd[0];
            out[0] = (float)e;
        }
    }
    int a = blockIdx.x * blockDim.x + threadIdx.x;
    if (a >= n) return;
    const float4* rec = (const float4*)(records + (size_t)a * 8);
    float4 r0 = rec[0];
    float4 r1 = rec[1];
    int packed = __float_as_int(r1.x);
    int i = __float_as_int(r1.y);
    int b0 = packed & 127, b1 = (packed >> 7) & 127, bz = (packed >> 14) & 127;
    float inv[9], det;
    inv3x3(cell, inv, &det);
    float wx[4], wy[4], wzv[4], dxv[4], dyv[4], dzv[4];
    bspline4(r0.x, wx, dxv);
    bspline4(r0.y, wy, dyv);
    bspline4(r0.z, wzv, dzv);
    int ix[4], iy[4];
#pragma unroll
    for (int j = 0; j < 4; j++) {
        ix[j] = (b0 - 3 + j + KDIM) & (KDIM - 1);
        iy[j] = (b1 - 3 + j + KDIM) & (KDIM - 1);
    }
    float acc0 = 0.0f, acc1 = 0.0f, acc2 = 0.0f;
    if (bz >= 3) {
        int z0 = bz - 3;
#pragma unroll
        for (int j0 = 0; j0 < 4; j0++) {
            int r0i = ix[j0] << 14;
            float wxx = wx[j0], dxx = dxv[j0];
#pragma unroll
            for (int j1 = 0; j1 < 4; j1++) {
                pf4 p = ld4u(&phi[r0i + (iy[j1] << 7) + z0]);
                float sw = p.a * wzv[0] + p.b * wzv[1] + p.c * wzv[2] + p.d * wzv[3];
                float sdz = p.a * dzv[0] + p.b * dzv[1] + p.c * dzv[2] + p.d * dzv[3];
                float wyy = wy[j1];
                acc0 += sw * dxx * wyy;
                acc1 += sw * wxx * dyv[j1];
                acc2 += sdz * wxx * wyy;
            }
        }
    } else {
        int iz[4];
#pragma unroll
        for (int j = 0; j < 4; j++) iz[j] = (bz - 3 + j + KDIM) & (KDIM - 1);
#pragma unroll
        for (int j0 = 0; j0 < 4; j0++) {
            int r0i = ix[j0] << 14;
            float wxx = wx[j0], dxx = dxv[j0];
#pragma unroll
            for (int j1 = 0; j1 < 4; j1++) {
                int r1i = r0i + (iy[j1] << 7);
                float sw = 0.0f, sdz = 0.0f;
#pragma unroll
                for (int j2 = 0; j2 < 4; j2++) {
                    float p = phi[r1i + iz[j2]];
                    sw += p * wzv[j2];
                    sdz += p * dzv[j2];
                }
                float wyy = wy[j1];
                acc0 += sw * dxx * wyy;
                acc1 += sw * wxx * dyv[j1];
                acc2 += sdz * wxx * wyy;
            }
        }
    }
    float qi = r0.w;
    float c = KE_F * TWO_PI_F / det;
    float fac = -2.0f * c * qi * (float)KDIM;
    out[1 + 3 * i + 0] = fac * (acc0 * inv[0] + acc1 * inv[1] + acc2 * inv[2]);
    out[1 + 3 * i + 1] = fac * (acc0 * inv[3] + acc1 * inv[4] + acc2 * inv[5]);
    out[1 + 3 * i + 2] = fac * (acc0 * inv[6] + acc1 * inv[7] + acc2 * inv[8]);
}

extern "C" void kernel_launch(void* const* d_in, const int* in_sizes, int n_in,
                              void* d_out, int out_size, void* d_ws, size_t ws_size,
                              hipStream_t stream) {
    const float* pos = (const float*)d_in[0];
    const float* chg = (const float*)d_in[1];
    const float* cell = (const float*)d_in[2];
    float* out = (float*)d_out;
    int n = in_sizes[1];
    int nb = (n + 255) / 256;

    char* w = (char*)d_ws;
    float2* C_t = (float2*)w;                     // NTOT float2; FFT uses planes 0..64
    size_t off = (size_t)NTOT * sizeof(float2);
    float* tiles = (float*)(w + off);             // 22.02 MB; phi aliases this
    off += (size_t)NBINS * TSTRIDE * sizeof(float);
    int* counts = (int*)(w + off);                // NBINS
    off += NBINS * sizeof(int);
    int* starts = (int*)(w + off);                // NBINS+1
    off += (NBINS + 1) * sizeof(int);
    int* aoff = (int*)(w + off);                  // n
    off += (size_t)n * sizeof(int);
    float* scale_part = (float*)(w + off);        // NSCALE_BLK
    off += NSCALE_BLK * sizeof(float);
    float* q2_part = (float*)(w + off);           // nb
    off += (size_t)nb * sizeof(float);
    float* mtblS = (float*)(w + off);             // 128
    off += KDIM * sizeof(float);
    float* btblS = (float*)(w + off);             // 128

    // records live in C_t's dead upper region (planes 65..127 never touched by FFT)
    float* records = (float*)(C_t + (size_t)NZKEEP * KDIM * KDIM);
    float* phi = (float*)tiles;                   // tiles dead after fft_z_merge

    zero_tbl_kernel<<<(NBINS + 255) / 256, 256, 0, stream>>>(counts, mtblS, btblS);
    hist_kernel<<<nb, 256, 0, stream>>>(pos, chg, cell, counts, aoff, q2_part, n);
    scan_kernel<<<1, 256, 0, stream>>>(counts, starts);
    scatter_kernel<<<nb, 256, 0, stream>>>(pos, chg, cell, starts, aoff, records, n);
    spread_bins_kernel<<<NBINS, 256, 0, stream>>>(records, starts, tiles);

    fft_z_merge<<<2048, 512, 0, stream>>>(tiles, C_t);          // fwd z, natural, s<=64
    fft_y<1><<<NZKEEP * KDIM / 8, 512, 0, stream>>>(C_t);       // fwd y (contiguous)
    fft_x_scale<<<NSCALE_BLK, 512, 0, stream>>>(C_t, cell, mtblS, btblS, scale_part);
    fft_y<0><<<NZKEEP * KDIM / 8, 512, 0, stream>>>(C_t);       // inv y (contiguous)
    fft_z_phi<<<KDIM * KDIM / 16, 512, 0, stream>>>(C_t, phi);  // inv z + Hermitian

    gather_kernel<<<nb, 256, 0, stream>>>(records, cell, phi, scale_part, q2_part, nb,
                                          out, n);
}